// Round 20
// baseline (167.617 us; speedup 1.0000x reference)
//
#include <hip/hip_runtime.h>
#include <hip/hip_fp16.h>

typedef _Float16 f16x8 __attribute__((ext_vector_type(8)));
typedef _Float16 f16x4 __attribute__((ext_vector_type(4)));
typedef float    f32x4 __attribute__((ext_vector_type(4)));

#define BATCH 131072

// ---------------------------------------------------------------------------
// Kernel 1: synthesize weights in 16x16x32 MFMA fragment order, 4-panel
// geometry (L1/L2: 4 panels x 128 n, NI=8; L3: 4 panels x 64 n, NI=4).
//   byte_off = ((pid*NW + w)*NI + ni)*1024 + lane*16 + j*2
//   n = pid*PANEL + ni*16 + (lane&15),  k = w*32 + (lane>>4)*8 + j
// Each wave wf load = ONE contiguous 1KB transaction.
// W[k][n] = tri(dist(p_i[k], p_{i+1}[n])) / sqrt(K).   [unchanged from R18]
// ---------------------------------------------------------------------------
__global__ void synth_weights_kernel(const float* __restrict__ p0, const float* __restrict__ p1,
                                     const float* __restrict__ p2, const float* __restrict__ p3,
                                     _Float16* __restrict__ blob0, _Float16* __restrict__ blob1,
                                     _Float16* __restrict__ blob2)
{
    const int idx = blockIdx.x * blockDim.x + threadIdx.x;   // 524288 total
    const float* A; const float* B; _Float16* Wt; float scl; int e, n, k;
    if (idx < 131072) {            // L1: K=256, NW=8,  NI=8, PANEL=128
        A = p0; B = p1; Wt = blob0; scl = 0.0625f; e = idx;
        const int j = e & 7, lane = (e >> 3) & 63, t = e >> 9;
        const int ni = t & 7, pw = t >> 3, w = pw & 7, pid = pw >> 3;
        n = pid * 128 + ni * 16 + (lane & 15);
        k = w * 32 + ((lane >> 4) << 3) + j;
    } else if (idx < 393216) {     // L2: K=512, NW=16, NI=8, PANEL=128
        A = p1; B = p2; Wt = blob1; scl = 0.04419417382415922f; e = idx - 131072;
        const int j = e & 7, lane = (e >> 3) & 63, t = e >> 9;
        const int ni = t & 7, pw = t >> 3, w = pw & 15, pid = pw >> 4;
        n = pid * 128 + ni * 16 + (lane & 15);
        k = w * 32 + ((lane >> 4) << 3) + j;
    } else {                       // L3: K=512, NW=16, NI=4, PANEL=64
        A = p2; B = p3; Wt = blob2; scl = 0.04419417382415922f; e = idx - 393216;
        const int j = e & 7, lane = (e >> 3) & 63, t = e >> 9;
        const int ni = t & 3, pw = t >> 2, w = pw & 15, pid = pw >> 4;
        n = pid * 64 + ni * 16 + (lane & 15);
        k = w * 32 + ((lane >> 4) << 3) + j;
    }
    float d2 = 0.f;
#pragma unroll
    for (int t = 0; t < 20; ++t) {
        float df = A[k * 20 + t] - B[n * 20 + t];
        d2 += df * df;
    }
    float d  = sqrtf(d2);
    float md = fmodf(d, 0.2f);                            // period 2P = 0.2, d >= 0
    float w  = 10.0f * (0.05f - fabsf(md - 0.1f)) * scl;  // AMP/P*(P-|m-P|-P/2)/sqrt(K)
    Wt[(size_t)e] = (_Float16)w;
}

// ---------------------------------------------------------------------------
// Fused MLP v20 = R18 + NON-TEMPORAL x-loads ONLY (R19 split-test):
//   - NT loads on x staging keep the 134 MB x stream out of L2 -> weight
//     blobs stay L2-resident (R19: FETCH 85.7->71.8 MB, MfmaUtil 31.8->36.5).
//   - Plain f32x4 out stores (R19's NT stores caused partial-line
//     write-through: WRITE 131->145.5 MB, clean-total regression).
// Everything else identical to R18: 256 thr / 4 waves, 64 rows, 64 KB LDS,
// 2 blocks/CU overlap, barrier-free k-loop, fragment-ordered blobs,
// full-line epilogue ordering.
// frag layouts (16x16x32, HW-verified R1-R19):
//   A/B input: index = lane&15, k = (lane>>4)*8 + j
//   D (swapped: mfma(wf, xf)): m = lane&15, n = (lane>>4)*4 + q (+16*ni)
// ---------------------------------------------------------------------------
__device__ __forceinline__ f16x8 ld_act(const char* act, int mi, int rl, int hi, int w)
{
    const int row = mi * 16 + rl;
    const int c   = w * 4 + hi;
    return *(const f16x8*)(act + row * 1024 + ((c ^ (row & 7)) << 4));
}

template<int NW, int NI, int MI>
__device__ __forceinline__ void mm_reg(const char* act, const _Float16* __restrict__ blob,
                                       int lane, int pid, f32x4 (&acc)[NI][MI])
{
    const int rl = lane & 15;
    const int hi = lane >> 4;
    const int ph = (pid * (NW / 4)) & (NW - 1);   // per-wave start window (4 waves)

    const char* wbase = (const char*)blob + ((size_t)pid * NW * NI) * 1024 + lane * 16;

    f16x8 wfA[NI], wfB[NI];
#pragma unroll
    for (int ni = 0; ni < NI; ++ni)
        wfA[ni] = *(const f16x8*)(wbase + (ph * NI + ni) * 1024);

#pragma unroll 1
    for (int w0 = 0; w0 < NW; w0 += 2) {
        const int wA = (w0 + ph) & (NW - 1);
        const int wB = (w0 + 1 + ph) & (NW - 1);
#pragma unroll
        for (int ni = 0; ni < NI; ++ni)
            wfB[ni] = *(const f16x8*)(wbase + (wB * NI + ni) * 1024);
        {
            f16x8 xf[MI];
#pragma unroll
            for (int mi = 0; mi < MI; ++mi) xf[mi] = ld_act(act, mi, rl, hi, wA);
            __builtin_amdgcn_s_setprio(1);
#pragma unroll
            for (int mi = 0; mi < MI; ++mi)
#pragma unroll
                for (int ni = 0; ni < NI; ++ni)
                    acc[ni][mi] = __builtin_amdgcn_mfma_f32_16x16x32_f16(wfA[ni], xf[mi], acc[ni][mi], 0, 0, 0);
            __builtin_amdgcn_s_setprio(0);
        }
        if (w0 + 2 < NW) {
            const int wC = (w0 + 2 + ph) & (NW - 1);
#pragma unroll
            for (int ni = 0; ni < NI; ++ni)
                wfA[ni] = *(const f16x8*)(wbase + (wC * NI + ni) * 1024);
        }
        {
            f16x8 xf[MI];
#pragma unroll
            for (int mi = 0; mi < MI; ++mi) xf[mi] = ld_act(act, mi, rl, hi, wB);
            __builtin_amdgcn_s_setprio(1);
#pragma unroll
            for (int mi = 0; mi < MI; ++mi)
#pragma unroll
                for (int ni = 0; ni < NI; ++ni)
                    acc[ni][mi] = __builtin_amdgcn_mfma_f32_16x16x32_f16(wfB[ni], xf[mi], acc[ni][mi], 0, 0, 0);
            __builtin_amdgcn_s_setprio(0);
        }
    }
}

// Write z (bias+relu) into act LDS [64][1024B] as 8B packs of 4 consecutive n.
template<int NI, int MI>
__device__ __forceinline__ void store_z(char* act, const float* __restrict__ bias,
                                        int wc, int lane, f32x4 (&acc)[NI][MI])
{
    const int rl = lane & 15;
    const int hi = lane >> 4;
#pragma unroll
    for (int ni = 0; ni < NI; ++ni) {
        const int n0 = wc + ni * 16 + hi * 4;
        const float4 bv = *(const float4*)(bias + n0);
#pragma unroll
        for (int mi = 0; mi < MI; ++mi) {
            const int m = mi * 16 + rl;
            f16x4 h;
            h[0] = (_Float16)fmaxf(acc[ni][mi][0] + bv.x, 0.0f);
            h[1] = (_Float16)fmaxf(acc[ni][mi][1] + bv.y, 0.0f);
            h[2] = (_Float16)fmaxf(acc[ni][mi][2] + bv.z, 0.0f);
            h[3] = (_Float16)fmaxf(acc[ni][mi][3] + bv.w, 0.0f);
            *(f16x4*)(act + m * 1024 + (((n0 >> 3) ^ (m & 7)) << 4) + (n0 & 7) * 2) = h;
        }
    }
}

__global__ __launch_bounds__(256, 2)
void fused_mlp_kernel(const float* __restrict__ x,
                      const _Float16* __restrict__ blob0, const _Float16* __restrict__ blob1,
                      const _Float16* __restrict__ blob2,
                      const float* __restrict__ b1, const float* __restrict__ b2,
                      const float* __restrict__ b3,
                      float* __restrict__ out)
{
    extern __shared__ char act[];             // 64 KB act slab
    const int tid  = threadIdx.x;
    const int lane = tid & 63;
    const int wid  = tid >> 6;                // 0..3 (n-panel id)
    const size_t m0 = (size_t)blockIdx.x * 64;

    // ---- stage x slab f32 -> f16 (NON-TEMPORAL loads: don't pollute L2)
#pragma unroll
    for (int it = 0; it < 8; ++it) {
        const int c   = it * 256 + tid;       // 2048 16B-chunks
        const int row = c >> 5;
        const int c8  = c & 31;
        const float* src = x + (m0 + row) * 256 + c8 * 8;
        const f32x4 v0 = __builtin_nontemporal_load((const f32x4*)src);
        const f32x4 v1 = __builtin_nontemporal_load((const f32x4*)(src + 4));
        f16x8 h;
        h[0] = (_Float16)v0[0]; h[1] = (_Float16)v0[1]; h[2] = (_Float16)v0[2]; h[3] = (_Float16)v0[3];
        h[4] = (_Float16)v1[0]; h[5] = (_Float16)v1[1]; h[6] = (_Float16)v1[2]; h[7] = (_Float16)v1[3];
        *(f16x8*)(act + row * 1024 + ((c8 ^ (row & 7)) << 4)) = h;
    }
    __syncthreads();

    const int wc = wid * 128;                 // wave's exclusive 128-n panel (L1/L2)

    // ---- layer 1: z1 = relu(x @ W0 + b1)   [64,256]@[256,512]
    {
        f32x4 acc[8][4] = {};
        mm_reg<8, 8, 4>(act, blob0, lane, wid, acc);
        __syncthreads();                      // all waves done reading x
        store_z<8, 4>(act, b1, wc, lane, acc);
        __syncthreads();
    }

    // ---- layer 2: z2 = relu(z1 @ W1 + b2)  [64,512]@[512,512]  (in-place)
    {
        f32x4 acc[8][4] = {};
        mm_reg<16, 8, 4>(act, blob1, lane, wid, acc);
        __syncthreads();
        store_z<8, 4>(act, b2, wc, lane, acc);
        __syncthreads();
    }

    // ---- layer 3: out = z2 @ W2 + b3       [64,512]@[512,256], plain f32x4
    //      stores, mi-outer / ni-inner: full 128B out-lines back-to-back.
    {
        const int wc3 = wid * 64;             // wave's exclusive 64-n panel
        f32x4 acc[4][4] = {};
        mm_reg<16, 4, 4>(act, blob2, lane, wid, acc);

        const int rl = lane & 15;
        const int hi = lane >> 4;
#pragma unroll
        for (int mi = 0; mi < 4; ++mi) {
            const size_t m = m0 + mi * 16 + rl;
#pragma unroll
            for (int ni = 0; ni < 4; ++ni) {
                const int n0 = wc3 + ni * 16 + hi * 4;
                const float4 bv = *(const float4*)(b3 + n0);
                f32x4 o;
                o[0] = acc[ni][mi][0] + bv.x;
                o[1] = acc[ni][mi][1] + bv.y;
                o[2] = acc[ni][mi][2] + bv.z;
                o[3] = acc[ni][mi][3] + bv.w;
                *(f32x4*)(out + m * 256 + n0) = o;
            }
        }
    }
}

// ---------------------------------------------------------------------------
// kernel_launch — ws: [blob0 256KB | blob1 512KB | blob2 256KB]
// ---------------------------------------------------------------------------
extern "C" void kernel_launch(void* const* d_in, const int* in_sizes, int n_in,
                              void* d_out, int out_size, void* d_ws, size_t ws_size,
                              hipStream_t stream)
{
    const float* x  = (const float*)d_in[0];
    const float* p0 = (const float*)d_in[1];
    const float* p1 = (const float*)d_in[2];
    const float* p2 = (const float*)d_in[3];
    const float* p3 = (const float*)d_in[4];
    const float* b1 = (const float*)d_in[5];
    const float* b2 = (const float*)d_in[6];
    const float* b3 = (const float*)d_in[7];

    char* ws = (char*)d_ws;
    _Float16* blob0 = (_Float16*)(ws);                    // 262144 B
    _Float16* blob1 = (_Float16*)(ws + 262144);           // 524288 B
    _Float16* blob2 = (_Float16*)(ws + 262144 + 524288);  // 262144 B

    synth_weights_kernel<<<2048, 256, 0, stream>>>(p0, p1, p2, p3, blob0, blob1, blob2);

    fused_mlp_kernel<<<BATCH / 64, 256, 65536, stream>>>(x, blob0, blob1, blob2,
                                                         b1, b2, b3, (float*)d_out);
}

// Round 21
// 158.119 us; speedup vs baseline: 1.0601x; 1.0601x over previous
//
#include <hip/hip_runtime.h>
#include <hip/hip_fp16.h>

typedef _Float16 f16x8 __attribute__((ext_vector_type(8)));
typedef _Float16 f16x4 __attribute__((ext_vector_type(4)));
typedef float    f32x4 __attribute__((ext_vector_type(4)));

#define BATCH 131072

// ---------------------------------------------------------------------------
// Kernel 1: synthesize weights in 16x16x32 MFMA fragment order, 4-panel
// geometry (L1/L2: 4 panels x 128 n, NI=8; L3: 4 panels x 64 n, NI=4).
//   byte_off = ((pid*NW + w)*NI + ni)*1024 + lane*16 + j*2
//   n = pid*PANEL + ni*16 + (lane&15),  k = w*32 + (lane>>4)*8 + j
// Each wave wf load = ONE contiguous 1KB transaction.
// W[k][n] = tri(dist(p_i[k], p_{i+1}[n])) / sqrt(K).
// ---------------------------------------------------------------------------
__global__ void synth_weights_kernel(const float* __restrict__ p0, const float* __restrict__ p1,
                                     const float* __restrict__ p2, const float* __restrict__ p3,
                                     _Float16* __restrict__ blob0, _Float16* __restrict__ blob1,
                                     _Float16* __restrict__ blob2)
{
    const int idx = blockIdx.x * blockDim.x + threadIdx.x;   // 524288 total
    const float* A; const float* B; _Float16* Wt; float scl; int e, n, k;
    if (idx < 131072) {            // L1: K=256, NW=8,  NI=8, PANEL=128
        A = p0; B = p1; Wt = blob0; scl = 0.0625f; e = idx;
        const int j = e & 7, lane = (e >> 3) & 63, t = e >> 9;
        const int ni = t & 7, pw = t >> 3, w = pw & 7, pid = pw >> 3;
        n = pid * 128 + ni * 16 + (lane & 15);
        k = w * 32 + ((lane >> 4) << 3) + j;
    } else if (idx < 393216) {     // L2: K=512, NW=16, NI=8, PANEL=128
        A = p1; B = p2; Wt = blob1; scl = 0.04419417382415922f; e = idx - 131072;
        const int j = e & 7, lane = (e >> 3) & 63, t = e >> 9;
        const int ni = t & 7, pw = t >> 3, w = pw & 15, pid = pw >> 4;
        n = pid * 128 + ni * 16 + (lane & 15);
        k = w * 32 + ((lane >> 4) << 3) + j;
    } else {                       // L3: K=512, NW=16, NI=4, PANEL=64
        A = p2; B = p3; Wt = blob2; scl = 0.04419417382415922f; e = idx - 393216;
        const int j = e & 7, lane = (e >> 3) & 63, t = e >> 9;
        const int ni = t & 3, pw = t >> 2, w = pw & 15, pid = pw >> 4;
        n = pid * 64 + ni * 16 + (lane & 15);
        k = w * 32 + ((lane >> 4) << 3) + j;
    }
    float d2 = 0.f;
#pragma unroll
    for (int t = 0; t < 20; ++t) {
        float df = A[k * 20 + t] - B[n * 20 + t];
        d2 += df * df;
    }
    float d  = sqrtf(d2);
    float md = fmodf(d, 0.2f);                            // period 2P = 0.2, d >= 0
    float w  = 10.0f * (0.05f - fabsf(md - 0.1f)) * scl;  // AMP/P*(P-|m-P|-P/2)/sqrt(K)
    Wt[(size_t)e] = (_Float16)w;
}

// ---------------------------------------------------------------------------
// Fused MLP (final, == R18): CROSS-BLOCK OVERLAP regime. 256 threads
// (4 waves), 64 rows/block, 64 KB LDS -> TWO independent blocks per CU at
// 2 w/SIMD (256-reg/wave budget). Block A's layer-boundary store_z/barrier/
// epilogue overlaps block B's k-loop. Per-wave tile 64m x 128n (NI=8, MI=4):
// acc 128 AGPR + wf 2x8 frags (64 VGPR) + xf 16 + addr ~= 120 VGPR.
//   - wf: coalesced fragment-ordered blob loads (1KB/wave/instr), depth-1
//     double-buffer, ph-staggered. Plain loads: weights + x both L3-resident;
//     NT variants (R19/R20) regressed clean timing by forcing HBM re-reads.
//   - xf: single-set LDS reads (lgkm hidden inside the 32-MFMA cluster).
//   - NO barriers in k-loop; barriers only around store_z.
// frag layouts (16x16x32, HW-verified R1-R20):
//   A/B input: index = lane&15, k = (lane>>4)*8 + j
//   D (swapped: mfma(wf, xf)): m = lane&15, n = (lane>>4)*4 + q (+16*ni)
// ---------------------------------------------------------------------------
__device__ __forceinline__ f16x8 ld_act(const char* act, int mi, int rl, int hi, int w)
{
    const int row = mi * 16 + rl;
    const int c   = w * 4 + hi;
    return *(const f16x8*)(act + row * 1024 + ((c ^ (row & 7)) << 4));
}

template<int NW, int NI, int MI>
__device__ __forceinline__ void mm_reg(const char* act, const _Float16* __restrict__ blob,
                                       int lane, int pid, f32x4 (&acc)[NI][MI])
{
    const int rl = lane & 15;
    const int hi = lane >> 4;
    const int ph = (pid * (NW / 4)) & (NW - 1);   // per-wave start window (4 waves)

    const char* wbase = (const char*)blob + ((size_t)pid * NW * NI) * 1024 + lane * 16;

    f16x8 wfA[NI], wfB[NI];
#pragma unroll
    for (int ni = 0; ni < NI; ++ni)
        wfA[ni] = *(const f16x8*)(wbase + (ph * NI + ni) * 1024);

#pragma unroll 1
    for (int w0 = 0; w0 < NW; w0 += 2) {
        const int wA = (w0 + ph) & (NW - 1);
        const int wB = (w0 + 1 + ph) & (NW - 1);
#pragma unroll
        for (int ni = 0; ni < NI; ++ni)
            wfB[ni] = *(const f16x8*)(wbase + (wB * NI + ni) * 1024);
        {
            f16x8 xf[MI];
#pragma unroll
            for (int mi = 0; mi < MI; ++mi) xf[mi] = ld_act(act, mi, rl, hi, wA);
            __builtin_amdgcn_s_setprio(1);
#pragma unroll
            for (int mi = 0; mi < MI; ++mi)
#pragma unroll
                for (int ni = 0; ni < NI; ++ni)
                    acc[ni][mi] = __builtin_amdgcn_mfma_f32_16x16x32_f16(wfA[ni], xf[mi], acc[ni][mi], 0, 0, 0);
            __builtin_amdgcn_s_setprio(0);
        }
        if (w0 + 2 < NW) {
            const int wC = (w0 + 2 + ph) & (NW - 1);
#pragma unroll
            for (int ni = 0; ni < NI; ++ni)
                wfA[ni] = *(const f16x8*)(wbase + (wC * NI + ni) * 1024);
        }
        {
            f16x8 xf[MI];
#pragma unroll
            for (int mi = 0; mi < MI; ++mi) xf[mi] = ld_act(act, mi, rl, hi, wB);
            __builtin_amdgcn_s_setprio(1);
#pragma unroll
            for (int mi = 0; mi < MI; ++mi)
#pragma unroll
                for (int ni = 0; ni < NI; ++ni)
                    acc[ni][mi] = __builtin_amdgcn_mfma_f32_16x16x32_f16(wfB[ni], xf[mi], acc[ni][mi], 0, 0, 0);
            __builtin_amdgcn_s_setprio(0);
        }
    }
}

// Write z (bias+relu) into act LDS [64][1024B] as 8B packs of 4 consecutive n.
template<int NI, int MI>
__device__ __forceinline__ void store_z(char* act, const float* __restrict__ bias,
                                        int wc, int lane, f32x4 (&acc)[NI][MI])
{
    const int rl = lane & 15;
    const int hi = lane >> 4;
#pragma unroll
    for (int ni = 0; ni < NI; ++ni) {
        const int n0 = wc + ni * 16 + hi * 4;
        const float4 bv = *(const float4*)(bias + n0);
#pragma unroll
        for (int mi = 0; mi < MI; ++mi) {
            const int m = mi * 16 + rl;
            f16x4 h;
            h[0] = (_Float16)fmaxf(acc[ni][mi][0] + bv.x, 0.0f);
            h[1] = (_Float16)fmaxf(acc[ni][mi][1] + bv.y, 0.0f);
            h[2] = (_Float16)fmaxf(acc[ni][mi][2] + bv.z, 0.0f);
            h[3] = (_Float16)fmaxf(acc[ni][mi][3] + bv.w, 0.0f);
            *(f16x4*)(act + m * 1024 + (((n0 >> 3) ^ (m & 7)) << 4) + (n0 & 7) * 2) = h;
        }
    }
}

__global__ __launch_bounds__(256, 2)
void fused_mlp_kernel(const float* __restrict__ x,
                      const _Float16* __restrict__ blob0, const _Float16* __restrict__ blob1,
                      const _Float16* __restrict__ blob2,
                      const float* __restrict__ b1, const float* __restrict__ b2,
                      const float* __restrict__ b3,
                      float* __restrict__ out)
{
    extern __shared__ char act[];             // 64 KB act slab
    const int tid  = threadIdx.x;
    const int lane = tid & 63;
    const int wid  = tid >> 6;                // 0..3 (n-panel id)
    const size_t m0 = (size_t)blockIdx.x * 64;

    // ---- stage x slab f32 -> f16 into act [64 rows][1024 B stride, 512 used]
#pragma unroll
    for (int it = 0; it < 8; ++it) {
        const int c   = it * 256 + tid;       // 2048 16B-chunks
        const int row = c >> 5;
        const int c8  = c & 31;
        const float* src = x + (m0 + row) * 256 + c8 * 8;
        const float4 v0 = *(const float4*)src;
        const float4 v1 = *(const float4*)(src + 4);
        f16x8 h;
        h[0] = (_Float16)v0.x; h[1] = (_Float16)v0.y; h[2] = (_Float16)v0.z; h[3] = (_Float16)v0.w;
        h[4] = (_Float16)v1.x; h[5] = (_Float16)v1.y; h[6] = (_Float16)v1.z; h[7] = (_Float16)v1.w;
        *(f16x8*)(act + row * 1024 + ((c8 ^ (row & 7)) << 4)) = h;
    }
    __syncthreads();

    const int wc = wid * 128;                 // wave's exclusive 128-n panel (L1/L2)

    // ---- layer 1: z1 = relu(x @ W0 + b1)   [64,256]@[256,512]
    {
        f32x4 acc[8][4] = {};
        mm_reg<8, 8, 4>(act, blob0, lane, wid, acc);
        __syncthreads();                      // all waves done reading x
        store_z<8, 4>(act, b1, wc, lane, acc);
        __syncthreads();
    }

    // ---- layer 2: z2 = relu(z1 @ W1 + b2)  [64,512]@[512,512]  (in-place)
    {
        f32x4 acc[8][4] = {};
        mm_reg<16, 8, 4>(act, blob1, lane, wid, acc);
        __syncthreads();
        store_z<8, 4>(act, b2, wc, lane, acc);
        __syncthreads();
    }

    // ---- layer 3: out = z2 @ W2 + b3       [64,512]@[512,256], direct f32
    //      mi-outer / ni-inner: full 128B out-lines back-to-back (R15-proven).
    {
        const int wc3 = wid * 64;             // wave's exclusive 64-n panel
        f32x4 acc[4][4] = {};
        mm_reg<16, 4, 4>(act, blob2, lane, wid, acc);

        const int rl = lane & 15;
        const int hi = lane >> 4;
#pragma unroll
        for (int mi = 0; mi < 4; ++mi) {
            const size_t m = m0 + mi * 16 + rl;
#pragma unroll
            for (int ni = 0; ni < 4; ++ni) {
                const int n0 = wc3 + ni * 16 + hi * 4;
                const float4 bv = *(const float4*)(b3 + n0);
                f32x4 o;
                o[0] = acc[ni][mi][0] + bv.x;
                o[1] = acc[ni][mi][1] + bv.y;
                o[2] = acc[ni][mi][2] + bv.z;
                o[3] = acc[ni][mi][3] + bv.w;
                *(f32x4*)(out + m * 256 + n0) = o;
            }
        }
    }
}

// ---------------------------------------------------------------------------
// kernel_launch — ws: [blob0 256KB | blob1 512KB | blob2 256KB]
// ---------------------------------------------------------------------------
extern "C" void kernel_launch(void* const* d_in, const int* in_sizes, int n_in,
                              void* d_out, int out_size, void* d_ws, size_t ws_size,
                              hipStream_t stream)
{
    const float* x  = (const float*)d_in[0];
    const float* p0 = (const float*)d_in[1];
    const float* p1 = (const float*)d_in[2];
    const float* p2 = (const float*)d_in[3];
    const float* p3 = (const float*)d_in[4];
    const float* b1 = (const float*)d_in[5];
    const float* b2 = (const float*)d_in[6];
    const float* b3 = (const float*)d_in[7];

    char* ws = (char*)d_ws;
    _Float16* blob0 = (_Float16*)(ws);                    // 262144 B
    _Float16* blob1 = (_Float16*)(ws + 262144);           // 524288 B
    _Float16* blob2 = (_Float16*)(ws + 262144 + 524288);  // 262144 B

    synth_weights_kernel<<<2048, 256, 0, stream>>>(p0, p1, p2, p3, blob0, blob1, blob2);

    fused_mlp_kernel<<<BATCH / 64, 256, 65536, stream>>>(x, blob0, blob1, blob2,
                                                         b1, b2, b3, (float*)d_out);
}